// Round 1
// baseline (184.115 us; speedup 1.0000x reference)
//
#include <hip/hip_runtime.h>

#define DEV __device__ __forceinline__

typedef __attribute__((ext_vector_type(8))) short bf16x8;
typedef __attribute__((ext_vector_type(4))) float f32x4;

constexpr int Bq = 16, Lq = 2048, Dq = 128, KW = 8;
constexpr int PROWS = Lq + KW - 1;   // 2055 padded positions per batch
constexpr int G3 = 3 * Dq;           // 384

DEV unsigned short f2bf(float f) {
    unsigned u = __float_as_uint(f);
    return (unsigned short)((u + 0x7FFFu + ((u >> 16) & 1u)) >> 16);
}
DEV float bf2f(unsigned short s) { return __uint_as_float(((unsigned)s) << 16); }

DEV float sigm(float x) { return __builtin_amdgcn_rcpf(1.f + __expf(-x)); }
DEV float tanh_(float x) {
    float e = __expf(2.f * x);
    return 1.f - 2.f * __builtin_amdgcn_rcpf(e + 1.f);
}

DEV bf16x8 pack8(float4 a, float4 b) {
    bf16x8 r;
    r[0] = (short)f2bf(a.x); r[1] = (short)f2bf(a.y);
    r[2] = (short)f2bf(a.z); r[3] = (short)f2bf(a.w);
    r[4] = (short)f2bf(b.x); r[5] = (short)f2bf(b.y);
    r[6] = (short)f2bf(b.z); r[7] = (short)f2bf(b.w);
    return r;
}
DEV int2 packbf4(float a, float b, float c, float d) {
    int2 r;
    r.x = (int)(((unsigned)f2bf(b) << 16) | (unsigned)f2bf(a));
    r.y = (int)(((unsigned)f2bf(d) << 16) | (unsigned)f2bf(c));
    return r;
}

// ---------------------------------------------------------------------------
// Kernel 1: Xp[b][p][g'] = (x[b][p-7] @ W_ih^T)[g] + b_ih[g] (+ b_hh[g] for r,z)
//   p in [0,7) are bias-only padding rows.  Stored bf16, g swizzled:
//   g' = g ^ ((p&7)<<3)  so the consumer's ds_read_b64 is conflict-free.
// ---------------------------------------------------------------------------
__global__ __launch_bounds__(256, 2) void k_proj(
    const float* __restrict__ x, const float* __restrict__ W_ih,
    const float* __restrict__ b_ih, const float* __restrict__ b_hh,
    unsigned short* __restrict__ Xp)
{
    if (blockIdx.x == 512) {  // padding rows
        for (int i = threadIdx.x; i < Bq * (KW - 1) * G3; i += 256) {
            int b = i / ((KW - 1) * G3);
            int rem = i - b * (KW - 1) * G3;
            int p = rem / G3;
            int g = rem - p * G3;
            float v = b_ih[g] + (g < 2 * Dq ? b_hh[g] : 0.f);
            int gs = g ^ ((p & 7) << 3);
            Xp[(size_t)(b * PROWS + p) * G3 + gs] = f2bf(v);
        }
        return;
    }
    __shared__ __attribute__((aligned(16))) unsigned char xls[64 * 256]; // 64 rows x 128 bf16, swizzled

    const int tid = threadIdx.x;
    const int lane = tid & 63, w = tid >> 6;
    const int l15 = lane & 15, l4 = lane >> 4;
    const int r0 = blockIdx.x * 64;  // global x-row base (same batch across tile)

    // stage x tile -> bf16 swizzled LDS
#pragma unroll
    for (int it = 0; it < 8; ++it) {
        int c = it * 256 + tid;           // 16B fp32 chunk, 2048 total
        int byte = c << 4;
        int row = byte >> 9;
        int wb = byte & 511;
        float4 v = *(const float4*)((const char*)(x + (size_t)r0 * Dq) + byte);
        int dst = row * 256 + ((wb >> 1) ^ ((row & 7) << 4));
        *(int2*)(xls + dst) = packbf4(v.x, v.y, v.z, v.w);
    }

    // A-fragments: W_ih rows [96w, 96w+96)
    bf16x8 afr[6][4];
#pragma unroll
    for (int mt = 0; mt < 6; ++mt)
#pragma unroll
        for (int kc = 0; kc < 4; ++kc) {
            int row = 96 * w + 16 * mt + l15;
            int k0 = 32 * kc + 8 * l4;
            const float* p = W_ih + row * Dq + k0;
            afr[mt][kc] = pack8(*(const float4*)p, *(const float4*)(p + 4));
        }
    float bias[6][4];
#pragma unroll
    for (int mt = 0; mt < 6; ++mt)
#pragma unroll
        for (int r = 0; r < 4; ++r) {
            int row = 96 * w + 16 * mt + 4 * l4 + r;
            bias[mt][r] = b_ih[row] + (row < 2 * Dq ? b_hh[row] : 0.f);
        }
    __syncthreads();

    f32x4 acc[6][4];
#pragma unroll
    for (int mt = 0; mt < 6; ++mt)
#pragma unroll
        for (int nt = 0; nt < 4; ++nt) {
            acc[mt][nt][0] = 0.f; acc[mt][nt][1] = 0.f;
            acc[mt][nt][2] = 0.f; acc[mt][nt][3] = 0.f;
        }

#pragma unroll
    for (int kc = 0; kc < 4; ++kc) {
        bf16x8 bfr[4];
#pragma unroll
        for (int nt = 0; nt < 4; ++nt) {
            int row = 16 * nt + l15;
            int off = row * 256 + ((64 * kc + 16 * l4) ^ ((row & 7) << 4));
            bfr[nt] = *(const bf16x8*)(xls + off);
        }
#pragma unroll
        for (int nt = 0; nt < 4; ++nt)
#pragma unroll
            for (int mt = 0; mt < 6; ++mt)
                acc[mt][nt] = __builtin_amdgcn_mfma_f32_16x16x32_bf16(
                    afr[mt][kc], bfr[nt], acc[mt][nt], 0, 0, 0);
    }

    const int b = r0 >> 11;
    const int lr0 = r0 & 2047;
#pragma unroll
    for (int mt = 0; mt < 6; ++mt)
#pragma unroll
        for (int nt = 0; nt < 4; ++nt) {
            int p = lr0 + 16 * nt + l15 + 7;
            int g0 = 96 * w + 16 * mt + 4 * l4;
            int gs = g0 ^ ((p & 7) << 3);
            size_t idx = (size_t)(b * PROWS + p) * G3 + gs;
            int2 pk = packbf4(acc[mt][nt][0] + bias[mt][0],
                              acc[mt][nt][1] + bias[mt][1],
                              acc[mt][nt][2] + bias[mt][2],
                              acc[mt][nt][3] + bias[mt][3]);
            *(int2*)(Xp + idx) = pk;
        }
}

// ---------------------------------------------------------------------------
// Kernel 2: fused local GRU.  Block = 64 windows, 8 waves; wave owns 16
// hidden units per gate.  h kept fp32 in registers (MFMA C/D layout),
// republished to swizzled LDS as bf16 each step for the B operand.
// C[gate-unit, window] = W_hh x h^T, accum fp32.
// ---------------------------------------------------------------------------
__global__ __launch_bounds__(512, 2) void k_rnn(
    const unsigned short* __restrict__ Xp, const float* __restrict__ W_hh,
    const float* __restrict__ b_hh, float* __restrict__ out)
{
    __shared__ __attribute__((aligned(16))) unsigned char xpt[71 * 768]; // 71 rows x 384 bf16 (pre-swizzled)
    __shared__ __attribute__((aligned(16))) unsigned char hls[64 * 256]; // 64 windows x 128 bf16, swizzled

    const int tid = threadIdx.x;
    const int lane = tid & 63, w = tid >> 6;
    const int l15 = lane & 15, l4 = lane >> 4;
    const int b = blockIdx.x >> 5;
    const int l0 = (blockIdx.x & 31) << 6;

    // A fragments: W_hh row = 128*g + 16*w + l15, k = 32*kc + 8*l4 + j
    bf16x8 afr[3][4];
#pragma unroll
    for (int g = 0; g < 3; ++g)
#pragma unroll
        for (int kc = 0; kc < 4; ++kc) {
            int row = 128 * g + 16 * w + l15;
            int k0 = 32 * kc + 8 * l4;
            const float* p = W_hh + row * Dq + k0;
            afr[g][kc] = pack8(*(const float4*)p, *(const float4*)(p + 4));
        }
    const int u0 = 16 * w + 4 * l4;
    f32x4 bhn4;
#pragma unroll
    for (int r = 0; r < 4; ++r) bhn4[r] = b_hh[2 * Dq + u0 + r];

    // stage Xp tile (linear 54528B copy; swizzle was pre-applied in global)
    {
        const unsigned short* src = Xp + (size_t)(b * PROWS + l0) * G3;
#pragma unroll
        for (int it = 0; it < 7; ++it) {
            int c = it * 512 + tid;
            if (c < 3408) ((int4*)xpt)[c] = ((const int4*)src)[c];
        }
    }
    // zero h in LDS (h0 = 0)
    {
        int4 z; z.x = 0; z.y = 0; z.z = 0; z.w = 0;
        ((int4*)hls)[2 * tid] = z;
        ((int4*)hls)[2 * tid + 1] = z;
    }
    __syncthreads();

    f32x4 h[4];
#pragma unroll
    for (int nt = 0; nt < 4; ++nt) { h[nt][0] = 0.f; h[nt][1] = 0.f; h[nt][2] = 0.f; h[nt][3] = 0.f; }

    for (int t = 0; t < 8; ++t) {
        f32x4 ar[4], az[4], an[4];
#pragma unroll
        for (int nt = 0; nt < 4; ++nt) {
            ar[nt][0] = 0.f; ar[nt][1] = 0.f; ar[nt][2] = 0.f; ar[nt][3] = 0.f;
            az[nt] = ar[nt];
            an[nt] = bhn4;  // fold b_hh(n) into accumulator init
        }
#pragma unroll
        for (int kc = 0; kc < 4; ++kc) {
            bf16x8 bfr[4];
#pragma unroll
            for (int nt = 0; nt < 4; ++nt) {
                int row = 16 * nt + l15;  // window
                int off = row * 256 + ((64 * kc + 16 * l4) ^ ((row & 7) << 4));
                bfr[nt] = *(const bf16x8*)(hls + off);
            }
#pragma unroll
            for (int nt = 0; nt < 4; ++nt) {
                ar[nt] = __builtin_amdgcn_mfma_f32_16x16x32_bf16(afr[0][kc], bfr[nt], ar[nt], 0, 0, 0);
                az[nt] = __builtin_amdgcn_mfma_f32_16x16x32_bf16(afr[1][kc], bfr[nt], az[nt], 0, 0, 0);
                an[nt] = __builtin_amdgcn_mfma_f32_16x16x32_bf16(afr[2][kc], bfr[nt], an[nt], 0, 0, 0);
            }
        }
#pragma unroll
        for (int nt = 0; nt < 4; ++nt) {
            int tr = 16 * nt + l15 + t;   // tile row (padded position - l0)
            int base = tr * G3;
            int s = (tr & 7) << 3;
            const ushort4 qr = *(const ushort4*)(xpt + 2 * (size_t)(base + ((0 * Dq + u0) ^ s)));
            const ushort4 qz = *(const ushort4*)(xpt + 2 * (size_t)(base + ((1 * Dq + u0) ^ s)));
            const ushort4 qn = *(const ushort4*)(xpt + 2 * (size_t)(base + ((2 * Dq + u0) ^ s)));
            float xr[4] = {bf2f(qr.x), bf2f(qr.y), bf2f(qr.z), bf2f(qr.w)};
            float xz[4] = {bf2f(qz.x), bf2f(qz.y), bf2f(qz.z), bf2f(qz.w)};
            float xn[4] = {bf2f(qn.x), bf2f(qn.y), bf2f(qn.z), bf2f(qn.w)};
#pragma unroll
            for (int r = 0; r < 4; ++r) {
                float rv = sigm(ar[nt][r] + xr[r]);
                float zv = sigm(az[nt][r] + xz[r]);
                float nv = tanh_(fmaf(rv, an[nt][r], xn[r]));
                h[nt][r] = nv + zv * (h[nt][r] - nv);
            }
        }
        __syncthreads();
#pragma unroll
        for (int nt = 0; nt < 4; ++nt) {
            int win = 16 * nt + l15;
            int off = win * 256 + ((2 * u0) ^ ((win & 7) << 4));
            *(int2*)(hls + off) = packbf4(h[nt][0], h[nt][1], h[nt][2], h[nt][3]);
        }
        __syncthreads();
    }

    // epilogue: h (fp32) -> out[b][l][u]
#pragma unroll
    for (int nt = 0; nt < 4; ++nt) {
        size_t idx = ((size_t)(b * Lq + l0 + 16 * nt + l15)) * Dq + u0;
        *(f32x4*)(out + idx) = h[nt];
    }
}

extern "C" void kernel_launch(void* const* d_in, const int* in_sizes, int n_in,
                              void* d_out, int out_size, void* d_ws, size_t ws_size,
                              hipStream_t stream) {
    const float* x    = (const float*)d_in[0];
    const float* W_ih = (const float*)d_in[1];
    const float* W_hh = (const float*)d_in[2];
    const float* b_ih = (const float*)d_in[3];
    const float* b_hh = (const float*)d_in[4];
    float* out = (float*)d_out;
    unsigned short* Xp = (unsigned short*)d_ws;  // [16][2055][384] bf16, 25.3 MB

    k_proj<<<dim3(513), dim3(256), 0, stream>>>(x, W_ih, b_ih, b_hh, Xp);
    k_rnn<<<dim3(512), dim3(512), 0, stream>>>(Xp, W_hh, b_hh, out);
}

// Round 2
// 167.798 us; speedup vs baseline: 1.0972x; 1.0972x over previous
//
#include <hip/hip_runtime.h>

#define DEV __device__ __forceinline__

typedef __attribute__((ext_vector_type(8))) short bf16x8;
typedef __attribute__((ext_vector_type(4))) float f32x4;

constexpr int Bq = 16, Lq = 2048, Dq = 128, KW = 8;
constexpr int G3 = 3 * Dq;           // 384

DEV unsigned short f2bf(float f) {
    unsigned u = __float_as_uint(f);
    return (unsigned short)((u + 0x7FFFu + ((u >> 16) & 1u)) >> 16);
}
DEV float bf2f(unsigned short s) { return __uint_as_float(((unsigned)s) << 16); }

DEV float sigm(float x) { return __builtin_amdgcn_rcpf(1.f + __expf(-x)); }
DEV float tanh_(float x) {
    float e = __expf(2.f * x);
    return 1.f - 2.f * __builtin_amdgcn_rcpf(e + 1.f);
}

DEV bf16x8 pack8(float4 a, float4 b) {
    bf16x8 r;
    r[0] = (short)f2bf(a.x); r[1] = (short)f2bf(a.y);
    r[2] = (short)f2bf(a.z); r[3] = (short)f2bf(a.w);
    r[4] = (short)f2bf(b.x); r[5] = (short)f2bf(b.y);
    r[6] = (short)f2bf(b.z); r[7] = (short)f2bf(b.w);
    return r;
}
DEV int2 packbf4(float a, float b, float c, float d) {
    int2 r;
    r.x = (int)(((unsigned)f2bf(b) << 16) | (unsigned)f2bf(a));
    r.y = (int)(((unsigned)f2bf(d) << 16) | (unsigned)f2bf(c));
    return r;
}

// ---------------------------------------------------------------------------
// Kernel 1: Xp[b][l][g'] = (x[b][l] @ W_ih^T)[g] + b_ih[g] (+ b_hh[g] for r,z)
//   Real rows only (no padding rows).  Stored bf16, g swizzled with the
//   CONSUMER's tile-row key:  g' = g ^ (((l+7)&7)<<3).
//   Epilogue stages the 64x384 bf16 tile in LDS (swizzled), then does a
//   fully-coalesced linear 16B/lane copy to global.
// ---------------------------------------------------------------------------
__global__ __launch_bounds__(256, 2) void k_proj(
    const float* __restrict__ x, const float* __restrict__ W_ih,
    const float* __restrict__ b_ih, const float* __restrict__ b_hh,
    unsigned short* __restrict__ Xp)
{
    __shared__ __attribute__((aligned(16))) unsigned char lds[64 * 768]; // 48KB: x-stage (16KB) then out-tile

    const int tid = threadIdx.x;
    const int lane = tid & 63, w = tid >> 6;
    const int l15 = lane & 15, l4 = lane >> 4;
    const int r0 = blockIdx.x * 64;  // global x-row base (same batch across tile)

    // stage x tile -> bf16 swizzled LDS (first 16KB)
#pragma unroll
    for (int it = 0; it < 8; ++it) {
        int c = it * 256 + tid;           // 16B fp32 chunk, 2048 total
        int byte = c << 4;
        int row = byte >> 9;
        int wb = byte & 511;
        float4 v = *(const float4*)((const char*)(x + (size_t)r0 * Dq) + byte);
        int dst = row * 256 + ((wb >> 1) ^ ((row & 7) << 4));
        *(int2*)(lds + dst) = packbf4(v.x, v.y, v.z, v.w);
    }

    // A-fragments: W_ih rows [96w, 96w+96)
    bf16x8 afr[6][4];
#pragma unroll
    for (int mt = 0; mt < 6; ++mt)
#pragma unroll
        for (int kc = 0; kc < 4; ++kc) {
            int row = 96 * w + 16 * mt + l15;
            int k0 = 32 * kc + 8 * l4;
            const float* p = W_ih + row * Dq + k0;
            afr[mt][kc] = pack8(*(const float4*)p, *(const float4*)(p + 4));
        }
    float bias[6][4];
#pragma unroll
    for (int mt = 0; mt < 6; ++mt)
#pragma unroll
        for (int r = 0; r < 4; ++r) {
            int row = 96 * w + 16 * mt + 4 * l4 + r;
            bias[mt][r] = b_ih[row] + (row < 2 * Dq ? b_hh[row] : 0.f);
        }
    __syncthreads();

    f32x4 acc[6][4];
#pragma unroll
    for (int mt = 0; mt < 6; ++mt)
#pragma unroll
        for (int nt = 0; nt < 4; ++nt) {
            acc[mt][nt][0] = 0.f; acc[mt][nt][1] = 0.f;
            acc[mt][nt][2] = 0.f; acc[mt][nt][3] = 0.f;
        }

#pragma unroll
    for (int kc = 0; kc < 4; ++kc) {
        bf16x8 bfr[4];
#pragma unroll
        for (int nt = 0; nt < 4; ++nt) {
            int row = 16 * nt + l15;
            int off = row * 256 + ((64 * kc + 16 * l4) ^ ((row & 7) << 4));
            bfr[nt] = *(const bf16x8*)(lds + off);
        }
#pragma unroll
        for (int nt = 0; nt < 4; ++nt)
#pragma unroll
            for (int mt = 0; mt < 6; ++mt)
                acc[mt][nt] = __builtin_amdgcn_mfma_f32_16x16x32_bf16(
                    afr[mt][kc], bfr[nt], acc[mt][nt], 0, 0, 0);
    }

    __syncthreads();  // x-stage reads done; reuse lds for the output tile

    // write acc -> LDS, pre-swizzled in element order the consumer expects
#pragma unroll
    for (int mt = 0; mt < 6; ++mt)
#pragma unroll
        for (int nt = 0; nt < 4; ++nt) {
            int r = 16 * nt + l15;            // local row (global l = r0 + r)
            int g = 96 * w + 16 * mt + 4 * l4;
            int sw = ((r + 7) & 7) << 3;      // consumer tile-row key: (l+7)&7
            int2 pk = packbf4(acc[mt][nt][0] + bias[mt][0],
                              acc[mt][nt][1] + bias[mt][1],
                              acc[mt][nt][2] + bias[mt][2],
                              acc[mt][nt][3] + bias[mt][3]);
            *(int2*)(lds + 2 * (size_t)(r * G3 + (g ^ sw))) = pk;
        }
    __syncthreads();

    // coalesced linear copy: 64 rows x 768B = 48KB
    {
        int4* dst = (int4*)(Xp + (size_t)r0 * G3);
#pragma unroll
        for (int it = 0; it < 12; ++it)
            dst[it * 256 + tid] = ((const int4*)lds)[it * 256 + tid];
    }
}

// ---------------------------------------------------------------------------
// Kernel 2: fused local GRU.  Block = 64 windows, 8 waves; wave owns 16
// hidden units per gate.  h kept fp32 in registers (MFMA C/D layout),
// republished to swizzled LDS as bf16 each step for the B operand.
// t=0 skips the hidden MFMA (h0 = 0).  Blocks with l0==0 synthesize the 7
// bias-only padding rows directly into the LDS tile.
// ---------------------------------------------------------------------------
__global__ __launch_bounds__(512, 2) void k_rnn(
    const unsigned short* __restrict__ Xp, const float* __restrict__ W_hh,
    const float* __restrict__ b_ih, const float* __restrict__ b_hh,
    float* __restrict__ out)
{
    __shared__ __attribute__((aligned(16))) unsigned char xpt[71 * 768]; // 71 rows x 384 bf16 (pre-swizzled)
    __shared__ __attribute__((aligned(16))) unsigned char hls[64 * 256]; // 64 windows x 128 bf16, swizzled

    const int tid = threadIdx.x;
    const int lane = tid & 63, w = tid >> 6;
    const int l15 = lane & 15, l4 = lane >> 4;
    const int b = blockIdx.x >> 5;
    const int l0 = (blockIdx.x & 31) << 6;

    // A fragments: W_hh row = 128*g + 16*w + l15, k = 32*kc + 8*l4 + j
    bf16x8 afr[3][4];
#pragma unroll
    for (int g = 0; g < 3; ++g)
#pragma unroll
        for (int kc = 0; kc < 4; ++kc) {
            int row = 128 * g + 16 * w + l15;
            int k0 = 32 * kc + 8 * l4;
            const float* p = W_hh + row * Dq + k0;
            afr[g][kc] = pack8(*(const float4*)p, *(const float4*)(p + 4));
        }
    const int u0 = 16 * w + 4 * l4;
    f32x4 bhn4;
#pragma unroll
    for (int r = 0; r < 4; ++r) bhn4[r] = b_hh[2 * Dq + u0 + r];

    // stage Xp tile rows: xpt row tr corresponds to x row l = l0 + tr - 7
    if (l0 == 0) {
        // rows 0..6: bias-only padding rows (swizzled by tr)
        for (int i = tid; i < 7 * G3; i += 512) {
            int tr = i / G3, g = i - tr * G3;
            float v = b_ih[g] + (g < 2 * Dq ? b_hh[g] : 0.f);
            ((unsigned short*)xpt)[tr * G3 + (g ^ ((tr & 7) << 3))] = f2bf(v);
        }
        const int4* src = (const int4*)(Xp + (size_t)b * Lq * G3);
#pragma unroll
        for (int it = 0; it < 6; ++it)
            ((int4*)(xpt + 7 * 768))[it * 512 + tid] = src[it * 512 + tid];
    } else {
        const int4* src = (const int4*)(Xp + ((size_t)b * Lq + l0 - 7) * G3);
        for (int c = tid; c < 71 * 48; c += 512)
            ((int4*)xpt)[c] = src[c];
    }
    __syncthreads();

    f32x4 h[4];
#pragma unroll
    for (int nt = 0; nt < 4; ++nt) { h[nt][0] = 0.f; h[nt][1] = 0.f; h[nt][2] = 0.f; h[nt][3] = 0.f; }

#pragma unroll
    for (int t = 0; t < 8; ++t) {
        f32x4 ar[4], az[4], an[4];
#pragma unroll
        for (int nt = 0; nt < 4; ++nt) {
            ar[nt][0] = 0.f; ar[nt][1] = 0.f; ar[nt][2] = 0.f; ar[nt][3] = 0.f;
            az[nt] = ar[nt];
            an[nt] = bhn4;  // fold b_hh(n) into accumulator init
        }
        if (t > 0) {
#pragma unroll
            for (int kc = 0; kc < 4; ++kc) {
                bf16x8 bfr[4];
#pragma unroll
                for (int nt = 0; nt < 4; ++nt) {
                    int row = 16 * nt + l15;  // window
                    int off = row * 256 + ((64 * kc + 16 * l4) ^ ((row & 7) << 4));
                    bfr[nt] = *(const bf16x8*)(hls + off);
                }
#pragma unroll
                for (int nt = 0; nt < 4; ++nt) {
                    ar[nt] = __builtin_amdgcn_mfma_f32_16x16x32_bf16(afr[0][kc], bfr[nt], ar[nt], 0, 0, 0);
                    az[nt] = __builtin_amdgcn_mfma_f32_16x16x32_bf16(afr[1][kc], bfr[nt], az[nt], 0, 0, 0);
                    an[nt] = __builtin_amdgcn_mfma_f32_16x16x32_bf16(afr[2][kc], bfr[nt], an[nt], 0, 0, 0);
                }
            }
        }
#pragma unroll
        for (int nt = 0; nt < 4; ++nt) {
            int tr = 16 * nt + l15 + t;   // tile row (padded position - l0)
            int base = tr * G3;
            int s = (tr & 7) << 3;
            const ushort4 qr = *(const ushort4*)(xpt + 2 * (size_t)(base + ((0 * Dq + u0) ^ s)));
            const ushort4 qz = *(const ushort4*)(xpt + 2 * (size_t)(base + ((1 * Dq + u0) ^ s)));
            const ushort4 qn = *(const ushort4*)(xpt + 2 * (size_t)(base + ((2 * Dq + u0) ^ s)));
            float xr[4] = {bf2f(qr.x), bf2f(qr.y), bf2f(qr.z), bf2f(qr.w)};
            float xz[4] = {bf2f(qz.x), bf2f(qz.y), bf2f(qz.z), bf2f(qz.w)};
            float xn[4] = {bf2f(qn.x), bf2f(qn.y), bf2f(qn.z), bf2f(qn.w)};
#pragma unroll
            for (int r = 0; r < 4; ++r) {
                float rv = sigm(ar[nt][r] + xr[r]);
                float zv = sigm(az[nt][r] + xz[r]);
                float nv = tanh_(fmaf(rv, an[nt][r], xn[r]));
                h[nt][r] = nv + zv * (h[nt][r] - nv);
            }
        }
        if (t < 7) {
            __syncthreads();
#pragma unroll
            for (int nt = 0; nt < 4; ++nt) {
                int win = 16 * nt + l15;
                int off = win * 256 + ((2 * u0) ^ ((win & 7) << 4));
                *(int2*)(hls + off) = packbf4(h[nt][0], h[nt][1], h[nt][2], h[nt][3]);
            }
            __syncthreads();
        }
    }

    // epilogue: h (fp32) -> out[b][l][u]
#pragma unroll
    for (int nt = 0; nt < 4; ++nt) {
        size_t idx = ((size_t)(b * Lq + l0 + 16 * nt + l15)) * Dq + u0;
        *(f32x4*)(out + idx) = h[nt];
    }
}

extern "C" void kernel_launch(void* const* d_in, const int* in_sizes, int n_in,
                              void* d_out, int out_size, void* d_ws, size_t ws_size,
                              hipStream_t stream) {
    const float* x    = (const float*)d_in[0];
    const float* W_ih = (const float*)d_in[1];
    const float* W_hh = (const float*)d_in[2];
    const float* b_ih = (const float*)d_in[3];
    const float* b_hh = (const float*)d_in[4];
    float* out = (float*)d_out;
    unsigned short* Xp = (unsigned short*)d_ws;  // [16][2048][384] bf16, 25.2 MB

    k_proj<<<dim3(512), dim3(256), 0, stream>>>(x, W_ih, b_ih, b_hh, Xp);
    k_rnn<<<dim3(512), dim3(512), 0, stream>>>(Xp, W_hh, b_ih, b_hh, out);
}

// Round 3
// 165.083 us; speedup vs baseline: 1.1153x; 1.0164x over previous
//
#include <hip/hip_runtime.h>

#define DEV __device__ __forceinline__

typedef __attribute__((ext_vector_type(8))) short bf16x8;
typedef __attribute__((ext_vector_type(4))) float f32x4;

constexpr int Bq = 16, Lq = 2048, Dq = 128, KW = 8;
constexpr int G3 = 3 * Dq;           // 384

DEV unsigned short f2bf(float f) {
    unsigned u = __float_as_uint(f);
    return (unsigned short)((u + 0x7FFFu + ((u >> 16) & 1u)) >> 16);
}
DEV float bf2f(unsigned short s) { return __uint_as_float(((unsigned)s) << 16); }

DEV float sigm(float x) { return __builtin_amdgcn_rcpf(1.f + __expf(-x)); }
DEV float tanh_(float x) {
    float e = __expf(2.f * x);
    return 1.f - 2.f * __builtin_amdgcn_rcpf(e + 1.f);
}

DEV bf16x8 pack8(float4 a, float4 b) {
    bf16x8 r;
    r[0] = (short)f2bf(a.x); r[1] = (short)f2bf(a.y);
    r[2] = (short)f2bf(a.z); r[3] = (short)f2bf(a.w);
    r[4] = (short)f2bf(b.x); r[5] = (short)f2bf(b.y);
    r[6] = (short)f2bf(b.z); r[7] = (short)f2bf(b.w);
    return r;
}
DEV int2 packbf4(float a, float b, float c, float d) {
    int2 r;
    r.x = (int)(((unsigned)f2bf(b) << 16) | (unsigned)f2bf(a));
    r.y = (int)(((unsigned)f2bf(d) << 16) | (unsigned)f2bf(c));
    return r;
}

// ---------------------------------------------------------------------------
// Kernel 1: Xp[b][l][g'] = (x[b][l] @ W_ih^T)[g] + b_ih[g] (+ b_hh[g] for r,z)
//   8 waves x 48 W-rows each (afr 48 + acc 48 VGPR -> no spill).
//   Stored bf16, g swizzled with the CONSUMER's tile-row key:
//   g' = g ^ (((l+7)&7)<<3).  Epilogue: LDS-staged, coalesced linear copy.
// ---------------------------------------------------------------------------
__global__ __launch_bounds__(512, 4) void k_proj(
    const float* __restrict__ x, const float* __restrict__ W_ih,
    const float* __restrict__ b_ih, const float* __restrict__ b_hh,
    unsigned short* __restrict__ Xp)
{
    __shared__ __attribute__((aligned(16))) unsigned char lds[64 * 768]; // 48KB: x-stage (16KB) then out-tile

    const int tid = threadIdx.x;
    const int lane = tid & 63, w = tid >> 6;      // w in [0,8)
    const int l15 = lane & 15, l4 = lane >> 4;
    const int r0 = blockIdx.x * 64;               // global x-row base

    // stage x tile -> bf16 swizzled LDS (first 16KB)
#pragma unroll
    for (int it = 0; it < 4; ++it) {
        int c = it * 512 + tid;           // 16B fp32 chunk, 2048 total
        int byte = c << 4;
        int row = byte >> 9;
        int wb = byte & 511;
        float4 v = *(const float4*)((const char*)(x + (size_t)r0 * Dq) + byte);
        int dst = row * 256 + ((wb >> 1) ^ ((row & 7) << 4));
        *(int2*)(lds + dst) = packbf4(v.x, v.y, v.z, v.w);
    }

    // A-fragments: W_ih rows [48w, 48w+48)
    bf16x8 afr[3][4];
#pragma unroll
    for (int mt = 0; mt < 3; ++mt)
#pragma unroll
        for (int kc = 0; kc < 4; ++kc) {
            int row = 48 * w + 16 * mt + l15;
            int k0 = 32 * kc + 8 * l4;
            const float* p = W_ih + row * Dq + k0;
            afr[mt][kc] = pack8(*(const float4*)p, *(const float4*)(p + 4));
        }
    float bias[3][4];
#pragma unroll
    for (int mt = 0; mt < 3; ++mt)
#pragma unroll
        for (int r = 0; r < 4; ++r) {
            int row = 48 * w + 16 * mt + 4 * l4 + r;
            bias[mt][r] = b_ih[row] + (row < 2 * Dq ? b_hh[row] : 0.f);
        }
    __syncthreads();

    f32x4 acc[3][4];
#pragma unroll
    for (int mt = 0; mt < 3; ++mt)
#pragma unroll
        for (int nt = 0; nt < 4; ++nt) {
            acc[mt][nt][0] = 0.f; acc[mt][nt][1] = 0.f;
            acc[mt][nt][2] = 0.f; acc[mt][nt][3] = 0.f;
        }

#pragma unroll
    for (int kc = 0; kc < 4; ++kc) {
        bf16x8 bfr[4];
#pragma unroll
        for (int nt = 0; nt < 4; ++nt) {
            int row = 16 * nt + l15;
            int off = row * 256 + ((64 * kc + 16 * l4) ^ ((row & 7) << 4));
            bfr[nt] = *(const bf16x8*)(lds + off);
        }
#pragma unroll
        for (int nt = 0; nt < 4; ++nt)
#pragma unroll
            for (int mt = 0; mt < 3; ++mt)
                acc[mt][nt] = __builtin_amdgcn_mfma_f32_16x16x32_bf16(
                    afr[mt][kc], bfr[nt], acc[mt][nt], 0, 0, 0);
    }

    __syncthreads();  // x-stage reads done; reuse lds for the output tile

    // write acc -> LDS, pre-swizzled in the element order the consumer expects
#pragma unroll
    for (int mt = 0; mt < 3; ++mt)
#pragma unroll
        for (int nt = 0; nt < 4; ++nt) {
            int r = 16 * nt + l15;            // local row (global l = r0 + r)
            int g = 48 * w + 16 * mt + 4 * l4;
            int sw = ((r + 7) & 7) << 3;      // consumer tile-row key: (l+7)&7
            int2 pk = packbf4(acc[mt][nt][0] + bias[mt][0],
                              acc[mt][nt][1] + bias[mt][1],
                              acc[mt][nt][2] + bias[mt][2],
                              acc[mt][nt][3] + bias[mt][3]);
            *(int2*)(lds + 2 * (size_t)(r * G3 + (g ^ sw))) = pk;
        }
    __syncthreads();

    // coalesced linear copy: 64 rows x 768B = 48KB = 3072 int4
    {
        int4* dst = (int4*)(Xp + (size_t)r0 * G3);
#pragma unroll
        for (int it = 0; it < 6; ++it)
            dst[it * 512 + tid] = ((const int4*)lds)[it * 512 + tid];
    }
}

// ---------------------------------------------------------------------------
// Kernel 2: fused local GRU.  Block = 32 windows, 8 waves; wave owns 16
// hidden units per gate (nt = 2 window-tiles).  h kept fp32 in registers
// (MFMA C/D layout), republished to swizzled LDS as bf16 each step for the
// B operand.  t=0 peeled (h0 = 0 -> no hidden MFMA, no hls init needed).
// Blocks with l0==0 synthesize the 7 bias-only padding rows into the tile.
// LDS 38KB -> 3 blocks/CU resident (VGPR-capped), phase-independent overlap.
// ---------------------------------------------------------------------------
__global__ __launch_bounds__(512, 4) void k_rnn(
    const unsigned short* __restrict__ Xp, const float* __restrict__ W_hh,
    const float* __restrict__ b_ih, const float* __restrict__ b_hh,
    float* __restrict__ out)
{
    __shared__ __attribute__((aligned(16))) unsigned char xpt[40 * 768]; // 39 used rows x 384 bf16 (pre-swizzled)
    __shared__ __attribute__((aligned(16))) unsigned char hls[32 * 256]; // 32 windows x 128 bf16, swizzled

    const int tid = threadIdx.x;
    const int lane = tid & 63, w = tid >> 6;
    const int l15 = lane & 15, l4 = lane >> 4;
    const int b = blockIdx.x >> 6;
    const int l0 = (blockIdx.x & 63) << 5;

    // A fragments: W_hh row = 128*g + 16*w + l15, k = 32*kc + 8*l4 + j
    bf16x8 afr[3][4];
#pragma unroll
    for (int g = 0; g < 3; ++g)
#pragma unroll
        for (int kc = 0; kc < 4; ++kc) {
            int row = 128 * g + 16 * w + l15;
            int k0 = 32 * kc + 8 * l4;
            const float* p = W_hh + row * Dq + k0;
            afr[g][kc] = pack8(*(const float4*)p, *(const float4*)(p + 4));
        }
    const int u0 = 16 * w + 4 * l4;
    f32x4 bhn4;
#pragma unroll
    for (int r = 0; r < 4; ++r) bhn4[r] = b_hh[2 * Dq + u0 + r];

    // stage Xp tile rows: xpt row tr corresponds to x row l = l0 + tr - 7
    if (l0 == 0) {
        // rows 0..6: bias-only padding rows (swizzled by tr&7)
        for (int i = tid; i < 7 * G3; i += 512) {
            int tr = i / G3, g = i - tr * G3;
            float v = b_ih[g] + (g < 2 * Dq ? b_hh[g] : 0.f);
            ((unsigned short*)xpt)[tr * G3 + (g ^ ((tr & 7) << 3))] = f2bf(v);
        }
        const int4* src = (const int4*)(Xp + (size_t)b * Lq * G3);
#pragma unroll
        for (int it = 0; it < 3; ++it)
            ((int4*)(xpt + 7 * 768))[it * 512 + tid] = src[it * 512 + tid];
    } else {
        const int4* src = (const int4*)(Xp + ((size_t)b * Lq + l0 - 7) * G3);
        for (int c = tid; c < 39 * 48; c += 512)
            ((int4*)xpt)[c] = src[c];
    }
    __syncthreads();

    f32x4 h[2];

    // ---- t = 0 (h0 == 0: gates come from xpt only) ----
#pragma unroll
    for (int nt = 0; nt < 2; ++nt) {
        int tr = 16 * nt + l15;
        int base = tr * G3;
        int s = (tr & 7) << 3;
        const ushort4 qr = *(const ushort4*)(xpt + 2 * (size_t)(base + ((0 * Dq + u0) ^ s)));
        const ushort4 qz = *(const ushort4*)(xpt + 2 * (size_t)(base + ((1 * Dq + u0) ^ s)));
        const ushort4 qn = *(const ushort4*)(xpt + 2 * (size_t)(base + ((2 * Dq + u0) ^ s)));
        float xr[4] = {bf2f(qr.x), bf2f(qr.y), bf2f(qr.z), bf2f(qr.w)};
        float xz[4] = {bf2f(qz.x), bf2f(qz.y), bf2f(qz.z), bf2f(qz.w)};
        float xn[4] = {bf2f(qn.x), bf2f(qn.y), bf2f(qn.z), bf2f(qn.w)};
#pragma unroll
        for (int r = 0; r < 4; ++r) {
            float rv = sigm(xr[r]);
            float zv = sigm(xz[r]);
            float nv = tanh_(fmaf(rv, bhn4[r], xn[r]));
            h[nt][r] = nv - zv * nv;   // h_prev = 0
        }
    }
#pragma unroll
    for (int nt = 0; nt < 2; ++nt) {
        int win = 16 * nt + l15;
        int off = win * 256 + ((2 * u0) ^ ((win & 7) << 4));
        *(int2*)(hls + off) = packbf4(h[nt][0], h[nt][1], h[nt][2], h[nt][3]);
    }
    __syncthreads();

    // ---- t = 1..7 ----
    for (int t = 1; t < 8; ++t) {
        f32x4 ar[2], az[2], an[2];
#pragma unroll
        for (int nt = 0; nt < 2; ++nt) {
            ar[nt][0] = 0.f; ar[nt][1] = 0.f; ar[nt][2] = 0.f; ar[nt][3] = 0.f;
            az[nt] = ar[nt];
            an[nt] = bhn4;  // fold b_hh(n) into accumulator init
        }
#pragma unroll
        for (int kc = 0; kc < 4; ++kc) {
            bf16x8 bfr[2];
#pragma unroll
            for (int nt = 0; nt < 2; ++nt) {
                int row = 16 * nt + l15;  // window
                int off = row * 256 + ((64 * kc + 16 * l4) ^ ((row & 7) << 4));
                bfr[nt] = *(const bf16x8*)(hls + off);
            }
#pragma unroll
            for (int nt = 0; nt < 2; ++nt) {
                ar[nt] = __builtin_amdgcn_mfma_f32_16x16x32_bf16(afr[0][kc], bfr[nt], ar[nt], 0, 0, 0);
                az[nt] = __builtin_amdgcn_mfma_f32_16x16x32_bf16(afr[1][kc], bfr[nt], az[nt], 0, 0, 0);
                an[nt] = __builtin_amdgcn_mfma_f32_16x16x32_bf16(afr[2][kc], bfr[nt], an[nt], 0, 0, 0);
            }
        }
#pragma unroll
        for (int nt = 0; nt < 2; ++nt) {
            int tr = 16 * nt + l15 + t;   // tile row (padded position - l0)
            int base = tr * G3;
            int s = (tr & 7) << 3;
            const ushort4 qr = *(const ushort4*)(xpt + 2 * (size_t)(base + ((0 * Dq + u0) ^ s)));
            const ushort4 qz = *(const ushort4*)(xpt + 2 * (size_t)(base + ((1 * Dq + u0) ^ s)));
            const ushort4 qn = *(const ushort4*)(xpt + 2 * (size_t)(base + ((2 * Dq + u0) ^ s)));
            float xr[4] = {bf2f(qr.x), bf2f(qr.y), bf2f(qr.z), bf2f(qr.w)};
            float xz[4] = {bf2f(qz.x), bf2f(qz.y), bf2f(qz.z), bf2f(qz.w)};
            float xn[4] = {bf2f(qn.x), bf2f(qn.y), bf2f(qn.z), bf2f(qn.w)};
#pragma unroll
            for (int r = 0; r < 4; ++r) {
                float rv = sigm(ar[nt][r] + xr[r]);
                float zv = sigm(az[nt][r] + xz[r]);
                float nv = tanh_(fmaf(rv, an[nt][r], xn[r]));
                h[nt][r] = nv + zv * (h[nt][r] - nv);
            }
        }
        if (t < 7) {
            __syncthreads();
#pragma unroll
            for (int nt = 0; nt < 2; ++nt) {
                int win = 16 * nt + l15;
                int off = win * 256 + ((2 * u0) ^ ((win & 7) << 4));
                *(int2*)(hls + off) = packbf4(h[nt][0], h[nt][1], h[nt][2], h[nt][3]);
            }
            __syncthreads();
        }
    }

    // epilogue: h (fp32) -> out[b][l][u]
#pragma unroll
    for (int nt = 0; nt < 2; ++nt) {
        size_t idx = ((size_t)(b * Lq + l0 + 16 * nt + l15)) * Dq + u0;
        *(f32x4*)(out + idx) = h[nt];
    }
}

extern "C" void kernel_launch(void* const* d_in, const int* in_sizes, int n_in,
                              void* d_out, int out_size, void* d_ws, size_t ws_size,
                              hipStream_t stream) {
    const float* x    = (const float*)d_in[0];
    const float* W_ih = (const float*)d_in[1];
    const float* W_hh = (const float*)d_in[2];
    const float* b_ih = (const float*)d_in[3];
    const float* b_hh = (const float*)d_in[4];
    float* out = (float*)d_out;
    unsigned short* Xp = (unsigned short*)d_ws;  // [16][2048][384] bf16, 25.2 MB

    k_proj<<<dim3(512), dim3(512), 0, stream>>>(x, W_ih, b_ih, b_hh, Xp);
    k_rnn<<<dim3(1024), dim3(512), 0, stream>>>(Xp, W_hh, b_ih, b_hh, out);
}

// Round 5
// 149.053 us; speedup vs baseline: 1.2352x; 1.1075x over previous
//
#include <hip/hip_runtime.h>
#include <hip/hip_bf16.h>

#define DEV __device__ __forceinline__

typedef __attribute__((ext_vector_type(8))) short bf16x8;
typedef __attribute__((ext_vector_type(4))) float f32x4;

constexpr int Bq = 16, Lq = 2048, Dq = 128, KW = 8;
constexpr int G3 = 3 * Dq;            // 384
constexpr float L2E = 1.4426950408889634f;   // log2(e)

DEV float exp2f_hw(float x) { return __builtin_amdgcn_exp2f(x); }  // v_exp_f32

DEV unsigned short f2bf(float f) {
    union { __hip_bfloat16 h; unsigned short u; } v;
    v.h = __float2bfloat16(f);
    return v.u;
}
DEV float bf2f(unsigned short s) { return __uint_as_float(((unsigned)s) << 16); }

// sigmoid(x) given y = x*log2e :  1/(1+2^-y)
DEV float sigm2(float y) { return __builtin_amdgcn_rcpf(1.f + exp2f_hw(-y)); }
// tanh(v) given y = 2v*log2e :  1 - 2/(2^y + 1)
DEV float tanh2(float y) {
    float e = exp2f_hw(y);
    return fmaf(-2.f, __builtin_amdgcn_rcpf(e + 1.f), 1.f);
}

DEV bf16x8 pack8s(float4 a, float4 b, float s) {
    bf16x8 r;
    r[0] = (short)f2bf(a.x * s); r[1] = (short)f2bf(a.y * s);
    r[2] = (short)f2bf(a.z * s); r[3] = (short)f2bf(a.w * s);
    r[4] = (short)f2bf(b.x * s); r[5] = (short)f2bf(b.y * s);
    r[6] = (short)f2bf(b.z * s); r[7] = (short)f2bf(b.w * s);
    return r;
}
DEV int2 packbf4(float a, float b, float c, float d) {
    int2 r;
    r.x = (int)(((unsigned)f2bf(b) << 16) | (unsigned)f2bf(a));
    r.y = (int)(((unsigned)f2bf(d) << 16) | (unsigned)f2bf(c));
    return r;
}

// ---------------------------------------------------------------------------
// Kernel 1: Xp[b][l][g'] = ((x[b][l] @ W_ih^T)[g] + bias[g]) * scale[g]
//   bias = b_ih (+ b_hh for r,z);  scale = log2e for r,z gates, 2*log2e for n.
//   Stored bf16, g swizzled with the CONSUMER's tile-row key:
//   g' = g ^ (((l+7)&7)<<3).  Epilogue: LDS-staged, coalesced linear copy.
// ---------------------------------------------------------------------------
__global__ __launch_bounds__(512, 4) void k_proj(
    const float* __restrict__ x, const float* __restrict__ W_ih,
    const float* __restrict__ b_ih, const float* __restrict__ b_hh,
    unsigned short* __restrict__ Xp)
{
    __shared__ __attribute__((aligned(16))) unsigned char lds[64 * 768]; // 48KB

    const int tid = threadIdx.x;
    const int lane = tid & 63, w = tid >> 6;      // w in [0,8)
    const int l15 = lane & 15, l4 = lane >> 4;
    const int r0 = blockIdx.x * 64;               // global x-row base

    // stage x tile -> bf16 swizzled LDS (first 16KB)
#pragma unroll
    for (int it = 0; it < 4; ++it) {
        int c = it * 512 + tid;           // 16B fp32 chunk, 2048 total
        int byte = c << 4;
        int row = byte >> 9;
        int wb = byte & 511;
        float4 v = *(const float4*)((const char*)(x + (size_t)r0 * Dq) + byte);
        int dst = row * 256 + ((wb >> 1) ^ ((row & 7) << 4));
        *(int2*)(lds + dst) = packbf4(v.x, v.y, v.z, v.w);
    }

    // A-fragments: W_ih rows [48w, 48w+48)
    bf16x8 afr[3][4];
#pragma unroll
    for (int mt = 0; mt < 3; ++mt)
#pragma unroll
        for (int kc = 0; kc < 4; ++kc) {
            int row = 48 * w + 16 * mt + l15;
            int k0 = 32 * kc + 8 * l4;
            const float* p = W_ih + row * Dq + k0;
            afr[mt][kc] = pack8s(*(const float4*)p, *(const float4*)(p + 4), 1.f);
        }
    float fs[3], bias[3][4];
#pragma unroll
    for (int mt = 0; mt < 3; ++mt) {
        int rbase = 48 * w + 16 * mt + 4 * l4;
        fs[mt] = (rbase < 2 * Dq) ? L2E : 2.f * L2E;
#pragma unroll
        for (int r = 0; r < 4; ++r) {
            int row = rbase + r;
            float bv = b_ih[row] + (row < 2 * Dq ? b_hh[row] : 0.f);
            bias[mt][r] = bv * fs[mt];
        }
    }
    __syncthreads();

    f32x4 acc[3][4];
#pragma unroll
    for (int mt = 0; mt < 3; ++mt)
#pragma unroll
        for (int nt = 0; nt < 4; ++nt) {
            acc[mt][nt][0] = 0.f; acc[mt][nt][1] = 0.f;
            acc[mt][nt][2] = 0.f; acc[mt][nt][3] = 0.f;
        }

#pragma unroll
    for (int kc = 0; kc < 4; ++kc) {
        bf16x8 bfr[4];
#pragma unroll
        for (int nt = 0; nt < 4; ++nt) {
            int row = 16 * nt + l15;
            int off = row * 256 + ((64 * kc + 16 * l4) ^ ((row & 7) << 4));
            bfr[nt] = *(const bf16x8*)(lds + off);
        }
#pragma unroll
        for (int nt = 0; nt < 4; ++nt)
#pragma unroll
            for (int mt = 0; mt < 3; ++mt)
                acc[mt][nt] = __builtin_amdgcn_mfma_f32_16x16x32_bf16(
                    afr[mt][kc], bfr[nt], acc[mt][nt], 0, 0, 0);
    }

    __syncthreads();  // x-stage reads done; reuse lds for the output tile

    // write acc -> LDS, scaled, pre-swizzled in consumer element order
#pragma unroll
    for (int mt = 0; mt < 3; ++mt)
#pragma unroll
        for (int nt = 0; nt < 4; ++nt) {
            int r = 16 * nt + l15;            // local row (global l = r0 + r)
            int g = 48 * w + 16 * mt + 4 * l4;
            int sw = ((r + 7) & 7) << 3;      // consumer tile-row key: (l+7)&7
            int2 pk = packbf4(fmaf(acc[mt][nt][0], fs[mt], bias[mt][0]),
                              fmaf(acc[mt][nt][1], fs[mt], bias[mt][1]),
                              fmaf(acc[mt][nt][2], fs[mt], bias[mt][2]),
                              fmaf(acc[mt][nt][3], fs[mt], bias[mt][3]));
            *(int2*)(lds + 2 * (size_t)(r * G3 + (g ^ sw))) = pk;
        }
    __syncthreads();

    // coalesced linear copy: 64 rows x 768B = 48KB = 3072 int4
    {
        int4* dst = (int4*)(Xp + (size_t)r0 * G3);
#pragma unroll
        for (int it = 0; it < 6; ++it)
            dst[it * 512 + tid] = ((const int4*)lds)[it * 512 + tid];
    }
}

// ---------------------------------------------------------------------------
// Kernel 2: fused local GRU.  Block = 64 windows, 8 waves; wave owns 16
// hidden units per gate (nt = 4).  h fp32 in registers (MFMA C/D layout),
// republished to swizzled LDS as bf16 each step.  t=0 peeled (h0 = 0).
// Gate inputs are pre-scaled by log2e (r,z) / 2log2e (n) -> exp2-form gates.
// 2 blocks/CU co-resident; grid 512 = all blocks resident (no tail).
// ---------------------------------------------------------------------------
__global__ __launch_bounds__(512, 4) void k_rnn(
    const unsigned short* __restrict__ Xp, const float* __restrict__ W_hh,
    const float* __restrict__ b_ih, const float* __restrict__ b_hh,
    float* __restrict__ out)
{
    __shared__ __attribute__((aligned(16))) unsigned char xpt[71 * 768]; // 54528B
    __shared__ __attribute__((aligned(16))) unsigned char hls[64 * 256]; // 16384B

    const int tid = threadIdx.x;
    const int lane = tid & 63, w = tid >> 6;
    const int l15 = lane & 15, l4 = lane >> 4;
    const int b = blockIdx.x >> 5;
    const int l0 = (blockIdx.x & 31) << 6;

    // A fragments: W_hh row = 128*g + 16*w + l15, scaled by gate factor
    bf16x8 afr[3][4];
#pragma unroll
    for (int g = 0; g < 3; ++g) {
        float fg = (g < 2) ? L2E : 2.f * L2E;
#pragma unroll
        for (int kc = 0; kc < 4; ++kc) {
            int row = 128 * g + 16 * w + l15;
            int k0 = 32 * kc + 8 * l4;
            const float* p = W_hh + row * Dq + k0;
            afr[g][kc] = pack8s(*(const float4*)p, *(const float4*)(p + 4), fg);
        }
    }
    const int u0 = 16 * w + 4 * l4;
    f32x4 bhn4;
#pragma unroll
    for (int r = 0; r < 4; ++r) bhn4[r] = b_hh[2 * Dq + u0 + r] * (2.f * L2E);

    // stage Xp tile rows: xpt row tr corresponds to x row l = l0 + tr - 7
    if (l0 == 0) {
        // rows 0..6: bias-only padding rows (scaled, swizzled by tr&7)
        for (int i = tid; i < 7 * G3; i += 512) {
            int tr = i / G3, g = i - tr * G3;
            float fg = (g < 2 * Dq) ? L2E : 2.f * L2E;
            float v = (b_ih[g] + (g < 2 * Dq ? b_hh[g] : 0.f)) * fg;
            ((unsigned short*)xpt)[tr * G3 + (g ^ ((tr & 7) << 3))] = f2bf(v);
        }
        const int4* src = (const int4*)(Xp + (size_t)b * Lq * G3);
#pragma unroll
        for (int it = 0; it < 6; ++it)
            ((int4*)(xpt + 7 * 768))[it * 512 + tid] = src[it * 512 + tid];
    } else {
        const int4* src = (const int4*)(Xp + ((size_t)b * Lq + l0 - 7) * G3);
        for (int c = tid; c < 71 * 48; c += 512)
            ((int4*)xpt)[c] = src[c];
    }
    __syncthreads();

    f32x4 h[4];

    // ---- t = 0 (h0 == 0: gates come from xpt only) ----
#pragma unroll
    for (int nt = 0; nt < 4; ++nt) {
        int tr = 16 * nt + l15;
        int base = tr * G3;
        int s = (tr & 7) << 3;
        const ushort4 qr = *(const ushort4*)(xpt + 2 * (size_t)(base + ((0 * Dq + u0) ^ s)));
        const ushort4 qz = *(const ushort4*)(xpt + 2 * (size_t)(base + ((1 * Dq + u0) ^ s)));
        const ushort4 qn = *(const ushort4*)(xpt + 2 * (size_t)(base + ((2 * Dq + u0) ^ s)));
        float xr[4] = {bf2f(qr.x), bf2f(qr.y), bf2f(qr.z), bf2f(qr.w)};
        float xz[4] = {bf2f(qz.x), bf2f(qz.y), bf2f(qz.z), bf2f(qz.w)};
        float xn[4] = {bf2f(qn.x), bf2f(qn.y), bf2f(qn.z), bf2f(qn.w)};
#pragma unroll
        for (int r = 0; r < 4; ++r) {
            float rv = sigm2(xr[r]);
            float zv = sigm2(xz[r]);
            float nv = tanh2(fmaf(rv, bhn4[r], xn[r]));
            h[nt][r] = nv - zv * nv;   // h_prev = 0
        }
    }
#pragma unroll
    for (int nt = 0; nt < 4; ++nt) {
        int win = 16 * nt + l15;
        int off = win * 256 + ((2 * u0) ^ ((win & 7) << 4));
        *(int2*)(hls + off) = packbf4(h[nt][0], h[nt][1], h[nt][2], h[nt][3]);
    }
    __syncthreads();

    // ---- t = 1..7 ----
    for (int t = 1; t < 8; ++t) {
        f32x4 ar[4], az[4], an[4];
#pragma unroll
        for (int nt = 0; nt < 4; ++nt) {
            ar[nt][0] = 0.f; ar[nt][1] = 0.f; ar[nt][2] = 0.f; ar[nt][3] = 0.f;
            az[nt] = ar[nt];
            an[nt] = bhn4;  // fold scaled b_hh(n) into accumulator init
        }
#pragma unroll
        for (int kc = 0; kc < 4; ++kc) {
            bf16x8 bfr[4];
#pragma unroll
            for (int nt = 0; nt < 4; ++nt) {
                int row = 16 * nt + l15;  // window
                int off = row * 256 + ((64 * kc + 16 * l4) ^ ((row & 7) << 4));
                bfr[nt] = *(const bf16x8*)(hls + off);
            }
#pragma unroll
            for (int nt = 0; nt < 4; ++nt) {
                ar[nt] = __builtin_amdgcn_mfma_f32_16x16x32_bf16(afr[0][kc], bfr[nt], ar[nt], 0, 0, 0);
                az[nt] = __builtin_amdgcn_mfma_f32_16x16x32_bf16(afr[1][kc], bfr[nt], az[nt], 0, 0, 0);
                an[nt] = __builtin_amdgcn_mfma_f32_16x16x32_bf16(afr[2][kc], bfr[nt], an[nt], 0, 0, 0);
            }
        }
#pragma unroll
        for (int nt = 0; nt < 4; ++nt) {
            int tr = 16 * nt + l15 + t;   // tile row (padded position - l0)
            int base = tr * G3;
            int s = (tr & 7) << 3;
            const ushort4 qr = *(const ushort4*)(xpt + 2 * (size_t)(base + ((0 * Dq + u0) ^ s)));
            const ushort4 qz = *(const ushort4*)(xpt + 2 * (size_t)(base + ((1 * Dq + u0) ^ s)));
            const ushort4 qn = *(const ushort4*)(xpt + 2 * (size_t)(base + ((2 * Dq + u0) ^ s)));
            float xr[4] = {bf2f(qr.x), bf2f(qr.y), bf2f(qr.z), bf2f(qr.w)};
            float xz[4] = {bf2f(qz.x), bf2f(qz.y), bf2f(qz.z), bf2f(qz.w)};
            float xn[4] = {bf2f(qn.x), bf2f(qn.y), bf2f(qn.z), bf2f(qn.w)};
#pragma unroll
            for (int r = 0; r < 4; ++r) {
                float rv = sigm2(ar[nt][r] + xr[r]);
                float zv = sigm2(az[nt][r] + xz[r]);
                float nv = tanh2(fmaf(rv, an[nt][r], xn[r]));
                h[nt][r] = nv + zv * (h[nt][r] - nv);
            }
        }
        if (t < 7) {
            __syncthreads();
#pragma unroll
            for (int nt = 0; nt < 4; ++nt) {
                int win = 16 * nt + l15;
                int off = win * 256 + ((2 * u0) ^ ((win & 7) << 4));
                *(int2*)(hls + off) = packbf4(h[nt][0], h[nt][1], h[nt][2], h[nt][3]);
            }
            __syncthreads();
        }
    }

    // epilogue: h (fp32) -> out[b][l][u]
#pragma unroll
    for (int nt = 0; nt < 4; ++nt) {
        size_t idx = ((size_t)(b * Lq + l0 + 16 * nt + l15)) * Dq + u0;
        *(f32x4*)(out + idx) = h[nt];
    }
}

extern "C" void kernel_launch(void* const* d_in, const int* in_sizes, int n_in,
                              void* d_out, int out_size, void* d_ws, size_t ws_size,
                              hipStream_t stream) {
    const float* x    = (const float*)d_in[0];
    const float* W_ih = (const float*)d_in[1];
    const float* W_hh = (const float*)d_in[2];
    const float* b_ih = (const float*)d_in[3];
    const float* b_hh = (const float*)d_in[4];
    float* out = (float*)d_out;
    unsigned short* Xp = (unsigned short*)d_ws;  // [16][2048][384] bf16, 25.2 MB

    k_proj<<<dim3(512), dim3(512), 0, stream>>>(x, W_ih, b_ih, b_hh, Xp);
    k_rnn<<<dim3(512), dim3(512), 0, stream>>>(Xp, W_hh, b_ih, b_hh, out);
}

// Round 6
// 144.659 us; speedup vs baseline: 1.2728x; 1.0304x over previous
//
#include <hip/hip_runtime.h>
#include <hip/hip_bf16.h>

#define DEV __device__ __forceinline__

typedef __attribute__((ext_vector_type(8))) short bf16x8;
typedef __attribute__((ext_vector_type(4))) float f32x4;

constexpr int Bq = 16, Lq = 2048, Dq = 128, KW = 8;
constexpr int G3 = 3 * Dq;            // 384
constexpr float L2E = 1.4426950408889634f;   // log2(e)

DEV float exp2f_hw(float x) { return __builtin_amdgcn_exp2f(x); }  // v_exp_f32

DEV unsigned short f2bf(float f) {
    union { __hip_bfloat16 h; unsigned short u; } v;
    v.h = __float2bfloat16(f);
    return v.u;
}
DEV float bf2f(unsigned short s) { return __uint_as_float(((unsigned)s) << 16); }

// sigmoid(x) given y = x*log2e :  1/(1+2^-y)
DEV float sigm2(float y) { return __builtin_amdgcn_rcpf(1.f + exp2f_hw(-y)); }
// tanh(v) given y = 2v*log2e :  1 - 2/(2^y + 1)
DEV float tanh2(float y) {
    float e = exp2f_hw(y);
    return fmaf(-2.f, __builtin_amdgcn_rcpf(e + 1.f), 1.f);
}

DEV bf16x8 pack8s(float4 a, float4 b, float s) {
    bf16x8 r;
    r[0] = (short)f2bf(a.x * s); r[1] = (short)f2bf(a.y * s);
    r[2] = (short)f2bf(a.z * s); r[3] = (short)f2bf(a.w * s);
    r[4] = (short)f2bf(b.x * s); r[5] = (short)f2bf(b.y * s);
    r[6] = (short)f2bf(b.z * s); r[7] = (short)f2bf(b.w * s);
    return r;
}
DEV int2 packbf4(float a, float b, float c, float d) {
    int2 r;
    r.x = (int)(((unsigned)f2bf(b) << 16) | (unsigned)f2bf(a));
    r.y = (int)(((unsigned)f2bf(d) << 16) | (unsigned)f2bf(c));
    return r;
}

// ---------------------------------------------------------------------------
// Kernel 1: Xp[b][l][g'] = ((x[b][l] @ W_ih^T)[g] + bias[g]) * scale[g]
//   bias = b_ih (+ b_hh for r,z);  scale = log2e for r,z gates, 2*log2e for n.
//   Stored bf16, g swizzled with the CONSUMER's tile-row key:
//   g' = g ^ (((l+7)&7)<<3).  Epilogue: LDS-staged, coalesced linear copy.
//   launch_bounds (512,2): 256-reg budget -> afr+acc fit, NO spills.
// ---------------------------------------------------------------------------
__global__ __launch_bounds__(512, 2) void k_proj(
    const float* __restrict__ x, const float* __restrict__ W_ih,
    const float* __restrict__ b_ih, const float* __restrict__ b_hh,
    unsigned short* __restrict__ Xp)
{
    __shared__ __attribute__((aligned(16))) unsigned char lds[64 * 768]; // 48KB

    const int tid = threadIdx.x;
    const int lane = tid & 63, w = tid >> 6;      // w in [0,8)
    const int l15 = lane & 15, l4 = lane >> 4;
    const int r0 = blockIdx.x * 64;               // global x-row base

    // stage x tile -> bf16 swizzled LDS (first 16KB)
#pragma unroll
    for (int it = 0; it < 4; ++it) {
        int c = it * 512 + tid;           // 16B fp32 chunk, 2048 total
        int byte = c << 4;
        int row = byte >> 9;
        int wb = byte & 511;
        float4 v = *(const float4*)((const char*)(x + (size_t)r0 * Dq) + byte);
        int dst = row * 256 + ((wb >> 1) ^ ((row & 7) << 4));
        *(int2*)(lds + dst) = packbf4(v.x, v.y, v.z, v.w);
    }

    // A-fragments: W_ih rows [48w, 48w+48)
    bf16x8 afr[3][4];
#pragma unroll
    for (int mt = 0; mt < 3; ++mt)
#pragma unroll
        for (int kc = 0; kc < 4; ++kc) {
            int row = 48 * w + 16 * mt + l15;
            int k0 = 32 * kc + 8 * l4;
            const float* p = W_ih + row * Dq + k0;
            afr[mt][kc] = pack8s(*(const float4*)p, *(const float4*)(p + 4), 1.f);
        }
    float fs[3], bias[3][4];
#pragma unroll
    for (int mt = 0; mt < 3; ++mt) {
        int rbase = 48 * w + 16 * mt + 4 * l4;
        fs[mt] = (rbase < 2 * Dq) ? L2E : 2.f * L2E;
#pragma unroll
        for (int r = 0; r < 4; ++r) {
            int row = rbase + r;
            float bv = b_ih[row] + (row < 2 * Dq ? b_hh[row] : 0.f);
            bias[mt][r] = bv * fs[mt];
        }
    }
    __syncthreads();

    f32x4 acc[3][4];
#pragma unroll
    for (int mt = 0; mt < 3; ++mt)
#pragma unroll
        for (int nt = 0; nt < 4; ++nt) {
            acc[mt][nt][0] = 0.f; acc[mt][nt][1] = 0.f;
            acc[mt][nt][2] = 0.f; acc[mt][nt][3] = 0.f;
        }

#pragma unroll
    for (int kc = 0; kc < 4; ++kc) {
        bf16x8 bfr[4];
#pragma unroll
        for (int nt = 0; nt < 4; ++nt) {
            int row = 16 * nt + l15;
            int off = row * 256 + ((64 * kc + 16 * l4) ^ ((row & 7) << 4));
            bfr[nt] = *(const bf16x8*)(lds + off);
        }
#pragma unroll
        for (int nt = 0; nt < 4; ++nt)
#pragma unroll
            for (int mt = 0; mt < 3; ++mt)
                acc[mt][nt] = __builtin_amdgcn_mfma_f32_16x16x32_bf16(
                    afr[mt][kc], bfr[nt], acc[mt][nt], 0, 0, 0);
    }

    __syncthreads();  // x-stage reads done; reuse lds for the output tile

    // write acc -> LDS, scaled, pre-swizzled in consumer element order
#pragma unroll
    for (int mt = 0; mt < 3; ++mt)
#pragma unroll
        for (int nt = 0; nt < 4; ++nt) {
            int r = 16 * nt + l15;            // local row (global l = r0 + r)
            int g = 48 * w + 16 * mt + 4 * l4;
            int sw = ((r + 7) & 7) << 3;      // consumer tile-row key: (l+7)&7
            int2 pk = packbf4(fmaf(acc[mt][nt][0], fs[mt], bias[mt][0]),
                              fmaf(acc[mt][nt][1], fs[mt], bias[mt][1]),
                              fmaf(acc[mt][nt][2], fs[mt], bias[mt][2]),
                              fmaf(acc[mt][nt][3], fs[mt], bias[mt][3]));
            *(int2*)(lds + 2 * (size_t)(r * G3 + (g ^ sw))) = pk;
        }
    __syncthreads();

    // coalesced linear copy: 64 rows x 768B = 48KB = 3072 int4
    {
        int4* dst = (int4*)(Xp + (size_t)r0 * G3);
#pragma unroll
        for (int it = 0; it < 6; ++it)
            dst[it * 512 + tid] = ((const int4*)lds)[it * 512 + tid];
    }
}

// ---------------------------------------------------------------------------
// Kernel 2: fused local GRU.  Block = 64 windows, 8 waves; wave owns 16
// hidden units per gate (nt = 4).  h fp32 in registers (MFMA C/D layout),
// republished to swizzled LDS as bf16 each step.  t=0 peeled (h0 = 0).
// Gate inputs pre-scaled by log2e (r,z) / 2log2e (n) -> exp2-form gates.
// launch_bounds (512,2): 256-reg budget (afr 48 + acc 48 + h 16 + temps
// all fit in VGPR+AGPR without spilling — (512,4)'s 128-cap spilled and
// cost +7us plus ~10MB of scratch traffic; see round-5 counters).
// ---------------------------------------------------------------------------
__global__ __launch_bounds__(512, 2) void k_rnn(
    const unsigned short* __restrict__ Xp, const float* __restrict__ W_hh,
    const float* __restrict__ b_ih, const float* __restrict__ b_hh,
    float* __restrict__ out)
{
    __shared__ __attribute__((aligned(16))) unsigned char xpt[71 * 768]; // 54528B
    __shared__ __attribute__((aligned(16))) unsigned char hls[64 * 256]; // 16384B

    const int tid = threadIdx.x;
    const int lane = tid & 63, w = tid >> 6;
    const int l15 = lane & 15, l4 = lane >> 4;
    const int b = blockIdx.x >> 5;
    const int l0 = (blockIdx.x & 31) << 6;

    // A fragments: W_hh row = 128*g + 16*w + l15, scaled by gate factor
    bf16x8 afr[3][4];
#pragma unroll
    for (int g = 0; g < 3; ++g) {
        float fg = (g < 2) ? L2E : 2.f * L2E;
#pragma unroll
        for (int kc = 0; kc < 4; ++kc) {
            int row = 128 * g + 16 * w + l15;
            int k0 = 32 * kc + 8 * l4;
            const float* p = W_hh + row * Dq + k0;
            afr[g][kc] = pack8s(*(const float4*)p, *(const float4*)(p + 4), fg);
        }
    }
    const int u0 = 16 * w + 4 * l4;
    f32x4 bhn4;
#pragma unroll
    for (int r = 0; r < 4; ++r) bhn4[r] = b_hh[2 * Dq + u0 + r] * (2.f * L2E);

    // stage Xp tile rows: xpt row tr corresponds to x row l = l0 + tr - 7
    if (l0 == 0) {
        // rows 0..6: bias-only padding rows (scaled, swizzled by tr&7)
        for (int i = tid; i < 7 * G3; i += 512) {
            int tr = i / G3, g = i - tr * G3;
            float fg = (g < 2 * Dq) ? L2E : 2.f * L2E;
            float v = (b_ih[g] + (g < 2 * Dq ? b_hh[g] : 0.f)) * fg;
            ((unsigned short*)xpt)[tr * G3 + (g ^ ((tr & 7) << 3))] = f2bf(v);
        }
        const int4* src = (const int4*)(Xp + (size_t)b * Lq * G3);
#pragma unroll
        for (int it = 0; it < 6; ++it)
            ((int4*)(xpt + 7 * 768))[it * 512 + tid] = src[it * 512 + tid];
    } else {
        const int4* src = (const int4*)(Xp + ((size_t)b * Lq + l0 - 7) * G3);
        for (int c = tid; c < 71 * 48; c += 512)
            ((int4*)xpt)[c] = src[c];
    }
    __syncthreads();

    f32x4 h[4];

    // ---- t = 0 (h0 == 0: gates come from xpt only) ----
#pragma unroll
    for (int nt = 0; nt < 4; ++nt) {
        int tr = 16 * nt + l15;
        int base = tr * G3;
        int s = (tr & 7) << 3;
        const ushort4 qr = *(const ushort4*)(xpt + 2 * (size_t)(base + ((0 * Dq + u0) ^ s)));
        const ushort4 qz = *(const ushort4*)(xpt + 2 * (size_t)(base + ((1 * Dq + u0) ^ s)));
        const ushort4 qn = *(const ushort4*)(xpt + 2 * (size_t)(base + ((2 * Dq + u0) ^ s)));
        float xr[4] = {bf2f(qr.x), bf2f(qr.y), bf2f(qr.z), bf2f(qr.w)};
        float xz[4] = {bf2f(qz.x), bf2f(qz.y), bf2f(qz.z), bf2f(qz.w)};
        float xn[4] = {bf2f(qn.x), bf2f(qn.y), bf2f(qn.z), bf2f(qn.w)};
#pragma unroll
        for (int r = 0; r < 4; ++r) {
            float rv = sigm2(xr[r]);
            float zv = sigm2(xz[r]);
            float nv = tanh2(fmaf(rv, bhn4[r], xn[r]));
            h[nt][r] = nv - zv * nv;   // h_prev = 0
        }
    }
#pragma unroll
    for (int nt = 0; nt < 4; ++nt) {
        int win = 16 * nt + l15;
        int off = win * 256 + ((2 * u0) ^ ((win & 7) << 4));
        *(int2*)(hls + off) = packbf4(h[nt][0], h[nt][1], h[nt][2], h[nt][3]);
    }
    __syncthreads();

    // ---- t = 1..7 ----
    for (int t = 1; t < 8; ++t) {
        f32x4 ar[4], az[4], an[4];
#pragma unroll
        for (int nt = 0; nt < 4; ++nt) {
            ar[nt][0] = 0.f; ar[nt][1] = 0.f; ar[nt][2] = 0.f; ar[nt][3] = 0.f;
            az[nt] = ar[nt];
            an[nt] = bhn4;  // fold scaled b_hh(n) into accumulator init
        }
#pragma unroll
        for (int kc = 0; kc < 4; ++kc) {
            bf16x8 bfr[4];
#pragma unroll
            for (int nt = 0; nt < 4; ++nt) {
                int row = 16 * nt + l15;  // window
                int off = row * 256 + ((64 * kc + 16 * l4) ^ ((row & 7) << 4));
                bfr[nt] = *(const bf16x8*)(hls + off);
            }
#pragma unroll
            for (int nt = 0; nt < 4; ++nt) {
                ar[nt] = __builtin_amdgcn_mfma_f32_16x16x32_bf16(afr[0][kc], bfr[nt], ar[nt], 0, 0, 0);
                az[nt] = __builtin_amdgcn_mfma_f32_16x16x32_bf16(afr[1][kc], bfr[nt], az[nt], 0, 0, 0);
                an[nt] = __builtin_amdgcn_mfma_f32_16x16x32_bf16(afr[2][kc], bfr[nt], an[nt], 0, 0, 0);
            }
        }
#pragma unroll
        for (int nt = 0; nt < 4; ++nt) {
            int tr = 16 * nt + l15 + t;   // tile row (padded position - l0)
            int base = tr * G3;
            int s = (tr & 7) << 3;
            const ushort4 qr = *(const ushort4*)(xpt + 2 * (size_t)(base + ((0 * Dq + u0) ^ s)));
            const ushort4 qz = *(const ushort4*)(xpt + 2 * (size_t)(base + ((1 * Dq + u0) ^ s)));
            const ushort4 qn = *(const ushort4*)(xpt + 2 * (size_t)(base + ((2 * Dq + u0) ^ s)));
            float xr[4] = {bf2f(qr.x), bf2f(qr.y), bf2f(qr.z), bf2f(qr.w)};
            float xz[4] = {bf2f(qz.x), bf2f(qz.y), bf2f(qz.z), bf2f(qz.w)};
            float xn[4] = {bf2f(qn.x), bf2f(qn.y), bf2f(qn.z), bf2f(qn.w)};
#pragma unroll
            for (int r = 0; r < 4; ++r) {
                float rv = sigm2(ar[nt][r] + xr[r]);
                float zv = sigm2(az[nt][r] + xz[r]);
                float nv = tanh2(fmaf(rv, an[nt][r], xn[r]));
                h[nt][r] = nv + zv * (h[nt][r] - nv);
            }
        }
        if (t < 7) {
            __syncthreads();
#pragma unroll
            for (int nt = 0; nt < 4; ++nt) {
                int win = 16 * nt + l15;
                int off = win * 256 + ((2 * u0) ^ ((win & 7) << 4));
                *(int2*)(hls + off) = packbf4(h[nt][0], h[nt][1], h[nt][2], h[nt][3]);
            }
            __syncthreads();
        }
    }

    // epilogue: h (fp32) -> out[b][l][u]
#pragma unroll
    for (int nt = 0; nt < 4; ++nt) {
        size_t idx = ((size_t)(b * Lq + l0 + 16 * nt + l15)) * Dq + u0;
        *(f32x4*)(out + idx) = h[nt];
    }
}

extern "C" void kernel_launch(void* const* d_in, const int* in_sizes, int n_in,
                              void* d_out, int out_size, void* d_ws, size_t ws_size,
                              hipStream_t stream) {
    const float* x    = (const float*)d_in[0];
    const float* W_ih = (const float*)d_in[1];
    const float* W_hh = (const float*)d_in[2];
    const float* b_ih = (const float*)d_in[3];
    const float* b_hh = (const float*)d_in[4];
    float* out = (float*)d_out;
    unsigned short* Xp = (unsigned short*)d_ws;  // [16][2048][384] bf16, 25.2 MB

    k_proj<<<dim3(512), dim3(512), 0, stream>>>(x, W_ih, b_ih, b_hh, Xp);
    k_rnn<<<dim3(512), dim3(512), 0, stream>>>(Xp, W_hh, b_ih, b_hh, out);
}

// Round 7
// 141.341 us; speedup vs baseline: 1.3026x; 1.0235x over previous
//
#include <hip/hip_runtime.h>
#include <hip/hip_bf16.h>

#define DEV __device__ __forceinline__

typedef __attribute__((ext_vector_type(8))) short bf16x8;
typedef __attribute__((ext_vector_type(4))) float f32x4;

constexpr int Bq = 16, Lq = 2048, Dq = 128;
constexpr int RZ = 2 * Dq;            // 256 (r,z gate rows)
constexpr int G3 = 3 * Dq;            // 384
constexpr float L2E = 1.4426950408889634f;   // log2(e)

DEV float exp2f_hw(float x) { return __builtin_amdgcn_exp2f(x); }  // v_exp_f32

DEV unsigned short f2bf(float f) {
    union { __hip_bfloat16 h; unsigned short u; } v;
    v.h = __float2bfloat16(f);
    return v.u;
}
DEV float bf2f(unsigned short s) { return __uint_as_float(((unsigned)s) << 16); }

// sigmoid(x) given y = x*log2e :  1/(1+2^-y)
DEV float sigm2(float y) { return __builtin_amdgcn_rcpf(1.f + exp2f_hw(-y)); }
// tanh(v) given y = 2v*log2e :  1 - 2/(2^y + 1)
DEV float tanh2(float y) {
    float e = exp2f_hw(y);
    return fmaf(-2.f, __builtin_amdgcn_rcpf(e + 1.f), 1.f);
}

DEV bf16x8 pack8s(float4 a, float4 b, float s) {
    bf16x8 r;
    r[0] = (short)f2bf(a.x * s); r[1] = (short)f2bf(a.y * s);
    r[2] = (short)f2bf(a.z * s); r[3] = (short)f2bf(a.w * s);
    r[4] = (short)f2bf(b.x * s); r[5] = (short)f2bf(b.y * s);
    r[6] = (short)f2bf(b.z * s); r[7] = (short)f2bf(b.w * s);
    return r;
}
DEV int2 packbf4(float a, float b, float c, float d) {
    int2 r;
    r.x = (int)(((unsigned)f2bf(b) << 16) | (unsigned)f2bf(a));
    r.y = (int)(((unsigned)f2bf(d) << 16) | (unsigned)f2bf(c));
    return r;
}

// ---------------------------------------------------------------------------
// Kernel 1: gate pre-projection, split into two dense arrays:
//   Xp_rz[b][l][g'] (g in [0,256), bias b_ih+b_hh, scale log2e)
//   Xp_n [b][l][u'] (u in [0,128), bias b_ih only,  scale 2*log2e)
//   both swizzled with the consumer's tile-row key: idx ^ (((l+7)&7)<<3).
// ---------------------------------------------------------------------------
__global__ __launch_bounds__(512, 2) void k_proj(
    const float* __restrict__ x, const float* __restrict__ W_ih,
    const float* __restrict__ b_ih, const float* __restrict__ b_hh,
    unsigned short* __restrict__ Xp_rz, unsigned short* __restrict__ Xp_n)
{
    __shared__ __attribute__((aligned(16))) unsigned char lds[64 * 768]; // 48KB

    const int tid = threadIdx.x;
    const int lane = tid & 63, w = tid >> 6;      // w in [0,8)
    const int l15 = lane & 15, l4 = lane >> 4;
    const int r0 = blockIdx.x * 64;               // global x-row base

    // stage x tile -> bf16 swizzled LDS (first 16KB)
#pragma unroll
    for (int it = 0; it < 4; ++it) {
        int c = it * 512 + tid;           // 16B fp32 chunk, 2048 total
        int byte = c << 4;
        int row = byte >> 9;
        int wb = byte & 511;
        float4 v = *(const float4*)((const char*)(x + (size_t)r0 * Dq) + byte);
        int dst = row * 256 + ((wb >> 1) ^ ((row & 7) << 4));
        *(int2*)(lds + dst) = packbf4(v.x, v.y, v.z, v.w);
    }

    // A-fragments: W_ih rows [48w, 48w+48)
    bf16x8 afr[3][4];
#pragma unroll
    for (int mt = 0; mt < 3; ++mt)
#pragma unroll
        for (int kc = 0; kc < 4; ++kc) {
            int row = 48 * w + 16 * mt + l15;
            int k0 = 32 * kc + 8 * l4;
            const float* p = W_ih + row * Dq + k0;
            afr[mt][kc] = pack8s(*(const float4*)p, *(const float4*)(p + 4), 1.f);
        }
    float fs[3], bias[3][4];
#pragma unroll
    for (int mt = 0; mt < 3; ++mt) {
        int rbase = 48 * w + 16 * mt + 4 * l4;
        fs[mt] = (rbase < RZ) ? L2E : 2.f * L2E;
#pragma unroll
        for (int r = 0; r < 4; ++r) {
            int row = rbase + r;
            float bv = b_ih[row] + (row < RZ ? b_hh[row] : 0.f);
            bias[mt][r] = bv * fs[mt];
        }
    }
    __syncthreads();

    f32x4 acc[3][4];
#pragma unroll
    for (int mt = 0; mt < 3; ++mt)
#pragma unroll
        for (int nt = 0; nt < 4; ++nt) {
            acc[mt][nt][0] = 0.f; acc[mt][nt][1] = 0.f;
            acc[mt][nt][2] = 0.f; acc[mt][nt][3] = 0.f;
        }

#pragma unroll
    for (int kc = 0; kc < 4; ++kc) {
        bf16x8 bfr[4];
#pragma unroll
        for (int nt = 0; nt < 4; ++nt) {
            int row = 16 * nt + l15;
            int off = row * 256 + ((64 * kc + 16 * l4) ^ ((row & 7) << 4));
            bfr[nt] = *(const bf16x8*)(lds + off);
        }
#pragma unroll
        for (int nt = 0; nt < 4; ++nt)
#pragma unroll
            for (int mt = 0; mt < 3; ++mt)
                acc[mt][nt] = __builtin_amdgcn_mfma_f32_16x16x32_bf16(
                    afr[mt][kc], bfr[nt], acc[mt][nt], 0, 0, 0);
    }

    __syncthreads();  // x-stage reads done; reuse lds for the output tiles:
                      // [0,32768): rz tile 64x512B; [32768,49152): n tile 64x256B

#pragma unroll
    for (int mt = 0; mt < 3; ++mt)
#pragma unroll
        for (int nt = 0; nt < 4; ++nt) {
            int r = 16 * nt + l15;            // local row (global l = r0 + r)
            int g = 48 * w + 16 * mt + 4 * l4;
            int sw = ((r + 7) & 7) << 3;      // consumer tile-row key
            int2 pk = packbf4(fmaf(acc[mt][nt][0], fs[mt], bias[mt][0]),
                              fmaf(acc[mt][nt][1], fs[mt], bias[mt][1]),
                              fmaf(acc[mt][nt][2], fs[mt], bias[mt][2]),
                              fmaf(acc[mt][nt][3], fs[mt], bias[mt][3]));
            if (48 * w + 16 * mt < RZ) {      // wave-uniform branch
                *(int2*)(lds + r * 512 + ((g ^ sw) << 1)) = pk;
            } else {
                int u = g - RZ;
                *(int2*)(lds + 32768 + r * 256 + ((u ^ sw) << 1)) = pk;
            }
        }
    __syncthreads();

    // coalesced linear copies
    {
        int4* dst = (int4*)(Xp_rz + (size_t)r0 * RZ);        // 32KB = 2048 int4
#pragma unroll
        for (int it = 0; it < 4; ++it)
            dst[it * 512 + tid] = ((const int4*)lds)[it * 512 + tid];
        int4* dstn = (int4*)(Xp_n + (size_t)r0 * Dq);        // 16KB = 1024 int4
        const int4* srcn = (const int4*)(lds + 32768);
#pragma unroll
        for (int it = 0; it < 2; ++it)
            dstn[it * 512 + tid] = srcn[it * 512 + tid];
    }
}

// ---------------------------------------------------------------------------
// Kernel 2: fused local GRU.  Block = 64 windows, 8 waves; wave owns 16
// hidden units per gate.  ONE barrier per step via double-buffered hls[2]:
// step t reads buf[(t-1)&1], writes buf[t&1], single end-of-step barrier.
// r,z gate inputs staged in LDS (xpt, 35.5KB) and folded into the MFMA
// C-init; n-gate inputs read directly from global (L2-resident Xp_n).
// t=0 peeled (h0 = 0).  LDS 67.5KB -> 2 blocks/CU; (512,2) -> no spills.
// ---------------------------------------------------------------------------
__global__ __launch_bounds__(512, 2) void k_rnn(
    const unsigned short* __restrict__ Xp_rz, const unsigned short* __restrict__ Xp_n,
    const float* __restrict__ W_hh, const float* __restrict__ b_ih,
    const float* __restrict__ b_hh, float* __restrict__ out)
{
    __shared__ __attribute__((aligned(16))) unsigned char xpt[71 * 512];     // 36352B
    __shared__ __attribute__((aligned(16))) unsigned char hls[2 * 64 * 256]; // 32768B

    const int tid = threadIdx.x;
    const int lane = tid & 63, w = tid >> 6;
    const int l15 = lane & 15, l4 = lane >> 4;
    const int b = blockIdx.x >> 5;
    const int l0 = (blockIdx.x & 31) << 6;

    // A fragments: W_hh row = 128*g + 16*w + l15, scaled by gate factor
    bf16x8 afr[3][4];
#pragma unroll
    for (int g = 0; g < 3; ++g) {
        float fg = (g < 2) ? L2E : 2.f * L2E;
#pragma unroll
        for (int kc = 0; kc < 4; ++kc) {
            int row = 128 * g + 16 * w + l15;
            int k0 = 32 * kc + 8 * l4;
            const float* p = W_hh + row * Dq + k0;
            afr[g][kc] = pack8s(*(const float4*)p, *(const float4*)(p + 4), fg);
        }
    }
    const int u0 = 16 * w + 4 * l4;
    f32x4 bhn4, bn4;
#pragma unroll
    for (int r = 0; r < 4; ++r) {
        bhn4[r] = b_hh[RZ + u0 + r] * (2.f * L2E);   // n-gate hidden bias (acc init)
        bn4[r]  = b_ih[RZ + u0 + r] * (2.f * L2E);   // n-gate pad value (xn for l<0)
    }

    // stage r,z tile rows: xpt row tr corresponds to x row l = l0 + tr - 7
    if (l0 == 0) {
        for (int i = tid; i < 7 * RZ; i += 512) {     // bias-only pad rows
            int tr = i >> 8, g = i & 255;
            float v = (b_ih[g] + b_hh[g]) * L2E;
            ((unsigned short*)xpt)[tr * RZ + (g ^ ((tr & 7) << 3))] = f2bf(v);
        }
        const int4* src = (const int4*)(Xp_rz + (size_t)b * Lq * RZ);
#pragma unroll
        for (int it = 0; it < 4; ++it)
            ((int4*)(xpt + 7 * 512))[it * 512 + tid] = src[it * 512 + tid];
    } else {
        const int4* src = (const int4*)(Xp_rz + ((size_t)b * Lq + l0 - 7) * RZ);
        for (int c = tid; c < 71 * 32; c += 512)
            ((int4*)xpt)[c] = src[c];
    }
    __syncthreads();

    f32x4 h[4];

    // ---- t = 0 (h0 == 0: gates from xpt / Xp_n only) ----
#pragma unroll
    for (int nt = 0; nt < 4; ++nt) {
        int tr = 16 * nt + l15;
        int s = (tr & 7) << 3;
        int ln = l0 + tr - 7;
        int lnc = ln < 0 ? 0 : ln;
        const ushort4 qn = *(const ushort4*)(Xp_n + (size_t)(b * Lq + lnc) * Dq + (u0 ^ s));
        const ushort4 qr = *(const ushort4*)(xpt + ((tr * RZ + (u0 ^ s)) << 1));
        const ushort4 qz = *(const ushort4*)(xpt + ((tr * RZ + ((Dq + u0) ^ s)) << 1));
        float xr[4] = {bf2f(qr.x), bf2f(qr.y), bf2f(qr.z), bf2f(qr.w)};
        float xz[4] = {bf2f(qz.x), bf2f(qz.y), bf2f(qz.z), bf2f(qz.w)};
        float xn[4] = {bf2f(qn.x), bf2f(qn.y), bf2f(qn.z), bf2f(qn.w)};
#pragma unroll
        for (int r = 0; r < 4; ++r) {
            float xnv = ln < 0 ? bn4[r] : xn[r];
            float rv = sigm2(xr[r]);
            float zv = sigm2(xz[r]);
            float nv = tanh2(fmaf(rv, bhn4[r], xnv));
            h[nt][r] = nv - zv * nv;   // h_prev = 0
        }
    }
#pragma unroll
    for (int nt = 0; nt < 4; ++nt) {
        int win = 16 * nt + l15;
        int off = win * 256 + ((2 * u0) ^ ((win & 7) << 4));
        *(int2*)(hls + off) = packbf4(h[nt][0], h[nt][1], h[nt][2], h[nt][3]);
    }
    __syncthreads();

    // ---- t = 1..7 : one barrier per step ----
    for (int t = 1; t < 8; ++t) {
        const int rdo = ((t - 1) & 1) << 14;   // read buffer byte offset
        const int wro = (t & 1) << 14;         // write buffer byte offset

        f32x4 ar[4], az[4], an[4];
        ushort4 qn_s[4];
        int ln_s[4];
#pragma unroll
        for (int nt = 0; nt < 4; ++nt) {
            int tr = 16 * nt + l15 + t;
            int s = (tr & 7) << 3;
            int ln = l0 + tr - 7;
            int lnc = ln < 0 ? 0 : ln;
            ln_s[nt] = ln;
            qn_s[nt] = *(const ushort4*)(Xp_n + (size_t)(b * Lq + lnc) * Dq + (u0 ^ s));
            const ushort4 qr = *(const ushort4*)(xpt + ((tr * RZ + (u0 ^ s)) << 1));
            const ushort4 qz = *(const ushort4*)(xpt + ((tr * RZ + ((Dq + u0) ^ s)) << 1));
            ar[nt][0] = bf2f(qr.x); ar[nt][1] = bf2f(qr.y);
            ar[nt][2] = bf2f(qr.z); ar[nt][3] = bf2f(qr.w);
            az[nt][0] = bf2f(qz.x); az[nt][1] = bf2f(qz.y);
            az[nt][2] = bf2f(qz.z); az[nt][3] = bf2f(qz.w);
            an[nt] = bhn4;
        }
#pragma unroll
        for (int kc = 0; kc < 4; ++kc) {
            bf16x8 bfr[4];
#pragma unroll
            for (int nt = 0; nt < 4; ++nt) {
                int row = 16 * nt + l15;  // window
                int off = rdo + row * 256 + ((64 * kc + 16 * l4) ^ ((row & 7) << 4));
                bfr[nt] = *(const bf16x8*)(hls + off);
            }
#pragma unroll
            for (int nt = 0; nt < 4; ++nt) {
                ar[nt] = __builtin_amdgcn_mfma_f32_16x16x32_bf16(afr[0][kc], bfr[nt], ar[nt], 0, 0, 0);
                az[nt] = __builtin_amdgcn_mfma_f32_16x16x32_bf16(afr[1][kc], bfr[nt], az[nt], 0, 0, 0);
                an[nt] = __builtin_amdgcn_mfma_f32_16x16x32_bf16(afr[2][kc], bfr[nt], an[nt], 0, 0, 0);
            }
        }
#pragma unroll
        for (int nt = 0; nt < 4; ++nt) {
            float xn[4] = {bf2f(qn_s[nt].x), bf2f(qn_s[nt].y),
                           bf2f(qn_s[nt].z), bf2f(qn_s[nt].w)};
#pragma unroll
            for (int r = 0; r < 4; ++r) {
                float xnv = ln_s[nt] < 0 ? bn4[r] : xn[r];
                float rv = sigm2(ar[nt][r]);
                float zv = sigm2(az[nt][r]);
                float nv = tanh2(fmaf(rv, an[nt][r], xnv));
                h[nt][r] = nv + zv * (h[nt][r] - nv);
            }
        }
        if (t < 7) {
#pragma unroll
            for (int nt = 0; nt < 4; ++nt) {
                int win = 16 * nt + l15;
                int off = wro + win * 256 + ((2 * u0) ^ ((win & 7) << 4));
                *(int2*)(hls + off) = packbf4(h[nt][0], h[nt][1], h[nt][2], h[nt][3]);
            }
            __syncthreads();
        }
    }

    // epilogue: h (fp32) -> out[b][l][u]
#pragma unroll
    for (int nt = 0; nt < 4; ++nt) {
        size_t idx = ((size_t)(b * Lq + l0 + 16 * nt + l15)) * Dq + u0;
        *(f32x4*)(out + idx) = h[nt];
    }
}

extern "C" void kernel_launch(void* const* d_in, const int* in_sizes, int n_in,
                              void* d_out, int out_size, void* d_ws, size_t ws_size,
                              hipStream_t stream) {
    const float* x    = (const float*)d_in[0];
    const float* W_ih = (const float*)d_in[1];
    const float* W_hh = (const float*)d_in[2];
    const float* b_ih = (const float*)d_in[3];
    const float* b_hh = (const float*)d_in[4];
    float* out = (float*)d_out;
    unsigned short* Xp_rz = (unsigned short*)d_ws;                    // [16][2048][256] bf16
    unsigned short* Xp_n  = Xp_rz + (size_t)Bq * Lq * RZ;             // [16][2048][128] bf16

    k_proj<<<dim3(512), dim3(512), 0, stream>>>(x, W_ih, b_ih, b_hh, Xp_rz, Xp_n);
    k_rnn<<<dim3(512), dim3(512), 0, stream>>>(Xp_rz, Xp_n, W_hh, b_ih, b_hh, out);
}